// Round 3
// baseline (748.025 us; speedup 1.0000x reference)
//
#include <hip/hip_runtime.h>
#include <cstdint>
#include <cstddef>

#define B_ 128
#define E_ 1024
#define R_ 64
#define T_ 4
#define IN_ 2112
#define G_ 256   // 4*R

typedef __attribute__((ext_vector_type(4))) float f32x4;
typedef __attribute__((ext_vector_type(8))) __bf16 bf16x8;

__device__ __forceinline__ unsigned short f2bf(float f) {
  unsigned int u = __float_as_uint(f);
  u += 0x7fffu + ((u >> 16) & 1u);   // RNE
  return (unsigned short)(u >> 16);
}
__device__ __forceinline__ unsigned int pack2(float lo, float hi) {
  return (unsigned int)f2bf(lo) | ((unsigned int)f2bf(hi) << 16);
}
__device__ __forceinline__ float wred_sum(float v) {
#pragma unroll
  for (int m = 32; m > 0; m >>= 1) v += __shfl_xor(v, m, 64);
  return v;
}
__device__ __forceinline__ float wred_max(float v) {
#pragma unroll
  for (int m = 32; m > 0; m >>= 1) v = fmaxf(v, __shfl_xor(v, m, 64));
  return v;
}
__device__ __forceinline__ float sigmoidf_(float x) { return 1.f / (1.f + expf(-x)); }

// ============ head: blocks [0,128) = LSTM recurrence (reg-cached weights,
//              1-barrier scan steps); blocks >=128 = kb fp32->bf16 conversion.
//              Fused so the conv streaming hides the LSTM's serial latency.
__global__ __launch_bounds__(256, 2) void head_kernel(
    const float* __restrict__ x, const float* __restrict__ kb,
    const float* __restrict__ Wih0, const float* __restrict__ Whh0,
    const float* __restrict__ bih0, const float* __restrict__ bhh0,
    const float* __restrict__ Wih, const float* __restrict__ Whh,
    const float* __restrict__ bih, const float* __restrict__ bhh,
    unsigned short* __restrict__ kb_bf,
    float* __restrict__ h2_out, float* __restrict__ att_out,
    unsigned short* __restrict__ prev_bf) {
  const int tid = threadIdx.x;

  if (blockIdx.x >= 128) {
    // ---- kb conversion: 64Mi elems over 8192 blocks, 32 elems/thread ----
    const size_t base = (size_t)(blockIdx.x - 128) * 8192;
#pragma unroll
    for (int c = 0; c < 4; c++) {
      size_t o = base + (size_t)c * 2048 + (size_t)tid * 8;
      float4 v0 = *(const float4*)(kb + o);
      float4 v1 = *(const float4*)(kb + o + 4);
      uint4 u;
      u.x = pack2(v0.x, v0.y); u.y = pack2(v0.z, v0.w);
      u.z = pack2(v1.x, v1.y); u.w = pack2(v1.z, v1.w);
      *(uint4*)(kb_bf + o) = u;
    }
    return;
  }

  __shared__ __align__(16) float xrow[IN_];
  __shared__ __align__(16) float hbuf[R_];
  __shared__ __align__(16) float zbuf[2][G_];
  __shared__ __align__(16) float hs_out[T_][R_];
  __shared__ __align__(16) float hmat[T_][R_];

  const int b = blockIdx.x;
  const int lane = tid & 63, wv = tid >> 6;
  const int s = tid & 63;

  // ---- fused pre0: stage x row, each thread g dots x[b,:].Wih0[g,:] ----
  for (int l = tid; l < IN_; l += 256) xrow[l] = x[b * IN_ + l];
  __syncthreads();
  float p0;
  {
    float4 acc4 = {0.f, 0.f, 0.f, 0.f};
    const float4* wr4 = (const float4*)(Wih0 + (size_t)tid * IN_);
    const float4* xr4 = (const float4*)xrow;
#pragma unroll 8
    for (int j = 0; j < IN_ / 4; j++) {
      float4 w = wr4[j];
      float4 xv = xr4[j];
      acc4.x += xv.x * w.x; acc4.y += xv.y * w.y;
      acc4.z += xv.z * w.z; acc4.w += xv.w * w.w;
    }
    p0 = bih0[tid] + bhh0[tid] + ((acc4.x + acc4.y) + (acc4.z + acc4.w));
  }

  float4 w4[16];   // 64 VGPRs: this thread's weight row (Whh or Wih), reg-cached
  float pret[T_];

  // scan over T_ steps; W row must already be in w4; pret[] precomputed.
  // One barrier per step; gates computed redundantly by all 4 waves.
  auto scan = [&]() {
    __syncthreads();                 // prior-layer gate writes fully done
    hbuf[s] = 0.f;                   // each wave zeroes all 64 (redundant, own-copy)
    float creg = 0.f;
#pragma unroll
    for (int t = 0; t < T_; t++) {
      float z = pret[t];
#pragma unroll
      for (int q = 0; q < 16; q++) {
        float4 hv = *(const float4*)(&hbuf[q * 4]);
        z += hv.x * w4[q].x + hv.y * w4[q].y + hv.z * w4[q].z + hv.w * w4[q].w;
      }
      zbuf[t & 1][tid] = z;
      __syncthreads();
      float iv = sigmoidf_(zbuf[t & 1][s]);
      float fv = sigmoidf_(zbuf[t & 1][R_ + s]);
      float gv = tanhf(zbuf[t & 1][2 * R_ + s]);
      float ov = sigmoidf_(zbuf[t & 1][3 * R_ + s]);
      creg = fv * creg + iv * gv;
      float h = ov * tanhf(creg);
      hbuf[s] = h;                   // redundant identical writes across waves
      hs_out[t][s] = h;
    }
  };

  // ---- layer 0 ----
#pragma unroll
  for (int t = 0; t < T_; t++) pret[t] = p0;
#pragma unroll
  for (int q = 0; q < 16; q++)
    w4[q] = *(const float4*)(Whh0 + (size_t)tid * R_ + q * 4);
  scan();

  // ---- layers 1..3 ----
  for (int l = 0; l < T_ - 1; l++) {
#pragma unroll
    for (int q = 0; q < 16; q++)
      w4[q] = *(const float4*)(Wih + ((size_t)l * G_ + tid) * R_ + q * 4);
    const float bsum = bih[l * G_ + tid] + bhh[l * G_ + tid];
#pragma unroll
    for (int t = 0; t < T_; t++) {
      float p = bsum;
#pragma unroll
      for (int q = 0; q < 16; q++) {
        float4 hv = *(const float4*)(&hs_out[t][q * 4]);
        p += hv.x * w4[q].x + hv.y * w4[q].y + hv.z * w4[q].z + hv.w * w4[q].w;
      }
      pret[t] = p;
    }
#pragma unroll
    for (int q = 0; q < 16; q++)
      w4[q] = *(const float4*)(Whh + ((size_t)l * G_ + tid) * R_ + q * 4);
    scan();
  }

  // ---- softmax head: wave wv handles timestep t = wv ----
  {
    float v = hs_out[wv][lane];
    float mx = wred_max(v);
    float ev = expf(v - mx);
    float sm = wred_sum(ev);
    float hval = ev / sm;                 // h = softmax(hs)
    hmat[wv][lane] = hval;
    float mx2 = wred_max(hval);
    float e2 = expf(hval - mx2);
    float s2 = wred_sum(e2);
    h2_out[(wv * B_ + b) * R_ + lane] = e2 / s2;   // h2 = softmax(h)
    __syncthreads();
    float dots[T_];
    for (int k = 0; k <= wv; k++)
      dots[k] = wred_sum(hmat[k][lane] * hmat[wv][lane]);
    if (lane == 0) {
      float mx3 = dots[0];
      for (int k = 1; k <= wv; k++) mx3 = fmaxf(mx3, dots[k]);
      float ss = 0.f, es[T_];
      for (int k = 0; k <= wv; k++) { es[k] = expf(dots[k] - mx3); ss += es[k]; }
      for (int k = 0; k <= wv; k++) att_out[(wv * B_ + b) * 4 + k] = es[k] / ss;
    }
  }

  // ---- fused prep0: att[0,b,0] == 1.0 exactly, so prev0 = bf16(x[b, R:R+E]) ----
  for (int l = tid; l < E_; l += 256)
    prev_bf[b * E_ + l] = f2bf(xrow[R_ + l]);
}

// ============ GEMM: part[r][b][e] = sum_f prev[b,f]*kb[r,e,f]  (bf16 MFMA) =======
// grid (8 e-tiles, 64 r), block 256. Tile 128x128, K=1024.
// NO LDS, NO barriers: B has zero reuse (each block reads a disjoint kbbf slice
// once), so fragments are loaded straight from global into registers, 2-deep
// double-buffered. Compiler emits counted vmcnt; waves keep ~16 loads in flight.
// Per-lane fragment data identical to the LDS version -> bitwise-same output.
__global__ __launch_bounds__(256) void gemm_bf_kernel(
    const unsigned short* __restrict__ Abf,   // [128][1024] bf16
    const unsigned short* __restrict__ Kbf,   // [64][1024][1024] bf16
    float* __restrict__ part) {               // [64][128][1024]
  const int tid = threadIdx.x, wv = tid >> 6, lane = tid & 63;
  const int et = blockIdx.x, r = blockIdx.y;
  const int wm = (wv & 1) * 64, wn = (wv >> 1) * 64;
  const int fr = lane & 15, koff = (lane >> 4) * 8;

  // per-lane fragment base pointers (k=0 column block)
  const unsigned short* ap[4];
  const unsigned short* bp[4];
#pragma unroll
  for (int mt = 0; mt < 4; mt++)
    ap[mt] = Abf + (size_t)(wm + mt * 16 + fr) * 1024 + koff;
#pragma unroll
  for (int nt = 0; nt < 4; nt++)
    bp[nt] = Kbf + (size_t)r * 1048576 +
             (size_t)(et * 128 + wn + nt * 16 + fr) * 1024 + koff;

  f32x4 acc[4][4];
#pragma unroll
  for (int mt = 0; mt < 4; mt++)
#pragma unroll
    for (int nt = 0; nt < 4; nt++)
#pragma unroll
      for (int q = 0; q < 4; q++) acc[mt][nt][q] = 0.f;

  bf16x8 a0[4], b0[4], a1[4], b1[4];
#pragma unroll
  for (int i = 0; i < 4; i++) {
    a0[i] = *(const bf16x8*)(ap[i]);
    b0[i] = *(const bf16x8*)(bp[i]);
  }

  for (int kk = 0; kk < 32; kk += 2) {
    // prefetch k-block kk+1 while computing kk
#pragma unroll
    for (int i = 0; i < 4; i++) {
      a1[i] = *(const bf16x8*)(ap[i] + (kk + 1) * 32);
      b1[i] = *(const bf16x8*)(bp[i] + (kk + 1) * 32);
    }
#pragma unroll
    for (int mt = 0; mt < 4; mt++)
#pragma unroll
      for (int nt = 0; nt < 4; nt++)
        acc[mt][nt] = __builtin_amdgcn_mfma_f32_16x16x32_bf16(a0[mt], b0[nt], acc[mt][nt], 0, 0, 0);
    if (kk + 2 < 32) {
      // prefetch k-block kk+2 while computing kk+1
#pragma unroll
      for (int i = 0; i < 4; i++) {
        a0[i] = *(const bf16x8*)(ap[i] + (kk + 2) * 32);
        b0[i] = *(const bf16x8*)(bp[i] + (kk + 2) * 32);
      }
    }
#pragma unroll
    for (int mt = 0; mt < 4; mt++)
#pragma unroll
      for (int nt = 0; nt < 4; nt++)
        acc[mt][nt] = __builtin_amdgcn_mfma_f32_16x16x32_bf16(a1[mt], b1[nt], acc[mt][nt], 0, 0, 0);
  }

  // C/D: col = lane&15, row = (lane>>4)*4 + q
  const int crow = (lane >> 4) * 4;
  float* pout = part + (size_t)r * 131072;
#pragma unroll
  for (int mt = 0; mt < 4; mt++)
#pragma unroll
    for (int nt = 0; nt < 4; nt++)
#pragma unroll
      for (int q = 0; q < 4; q++)
        pout[(wm + mt * 16 + crow + q) * 1024 + et * 128 + wn + nt * 16 + fr] = acc[mt][nt][q];
}

// ============ mid: mem_it = sum_r h2[it,b,r]*part[r,b,e]; prep next prev ========
__global__ __launch_bounds__(256) void mid_kernel(
    const float* __restrict__ part, const float* __restrict__ h2,
    const float* __restrict__ att, const float* __restrict__ x,
    float* __restrict__ mem, unsigned short* __restrict__ prev_bf, int it) {
  const int idx = blockIdx.x * 256 + threadIdx.x;   // 131072
  const int b = idx >> 10, e = idx & 1023;
  const float* h2row = h2 + (it * B_ + b) * R_;     // b uniform per block
  const float* pp = part + idx;
  float s = 0.f;
#pragma unroll 8
  for (int rr = 0; rr < 64; rr++) s += h2row[rr] * pp[(size_t)rr * 131072];
  mem[it * 131072 + idx] = s;
  if (it < 3) {
    const float* arow = att + ((it + 1) * B_ + b) * 4;
    float acc = arow[0] * x[b * IN_ + R_ + e];
    for (int k = 1; k <= it; k++) acc += arow[k] * mem[(k - 1) * 131072 + idx];
    acc += arow[it + 1] * s;
    prev_bf[idx] = f2bf(acc);
  }
}

// ============ fallback path (small ws): round-0 fp32-kb gemm ====================
__global__ __launch_bounds__(256) void prep_fp32_kernel(
    const float* __restrict__ x, const float* __restrict__ att,
    const float* __restrict__ mem, float* __restrict__ prev,
    float* __restrict__ newmem, int it) {
  const int idx = blockIdx.x * 256 + threadIdx.x;
  const int b = idx >> 10, e = idx & 1023;
  const float* arow = att + (it * B_ + b) * 4;
  float acc = arow[0] * x[b * IN_ + R_ + e];
  for (int k = 1; k <= it; k++)
    acc += arow[k] * mem[(k - 1) * (B_ * E_) + b * E_ + e];
  prev[idx] = acc;
  newmem[idx] = 0.f;
}

__global__ __launch_bounds__(256) void gemm_fp32_kernel(
    const float* __restrict__ prev, const float* __restrict__ h2,
    const float* __restrict__ kb, float* __restrict__ out) {
  __shared__ unsigned short As[128 * 40];
  __shared__ unsigned short Bs[128 * 40];
  __shared__ float h2s[128];
  const int tid = threadIdx.x;
  const int et = blockIdx.x;
  const int r = blockIdx.y;
  if (tid < 128) h2s[tid] = h2[tid * 64 + r];
  __syncthreads();
  const int row = tid >> 1;
  const int c0 = (tid & 1) * 16;
  const float hsc = h2s[row];
  const float* aptr = prev + row * 1024 + c0;
  const float* bptr = kb + (size_t)r * (1024u * 1024u) + (size_t)(et * 128 + row) * 1024 + c0;
  unsigned short* adst = As + row * 40 + c0;
  unsigned short* bdst = Bs + row * 40 + c0;
  const int wv = tid >> 6, lane = tid & 63;
  const int wm = (wv & 1) * 64, wn = (wv >> 1) * 64;
  const int fr = lane & 15, koff = (lane >> 4) * 8;
  f32x4 acc[4][4];
#pragma unroll
  for (int mt = 0; mt < 4; mt++)
#pragma unroll
    for (int nt = 0; nt < 4; nt++)
#pragma unroll
      for (int q = 0; q < 4; q++) acc[mt][nt][q] = 0.f;
  for (int kk = 0; kk < 32; kk++) {
    const float4 a0 = *(const float4*)(aptr + kk * 32);
    const float4 a1 = *(const float4*)(aptr + kk * 32 + 4);
    const float4 a2 = *(const float4*)(aptr + kk * 32 + 8);
    const float4 a3 = *(const float4*)(aptr + kk * 32 + 12);
    const float4 b0 = *(const float4*)(bptr + kk * 32);
    const float4 b1 = *(const float4*)(bptr + kk * 32 + 4);
    const float4 b2 = *(const float4*)(bptr + kk * 32 + 8);
    const float4 b3 = *(const float4*)(bptr + kk * 32 + 12);
    __syncthreads();
    uint4 u;
    u.x = pack2(a0.x * hsc, a0.y * hsc); u.y = pack2(a0.z * hsc, a0.w * hsc);
    u.z = pack2(a1.x * hsc, a1.y * hsc); u.w = pack2(a1.z * hsc, a1.w * hsc);
    *(uint4*)adst = u;
    u.x = pack2(a2.x * hsc, a2.y * hsc); u.y = pack2(a2.z * hsc, a2.w * hsc);
    u.z = pack2(a3.x * hsc, a3.y * hsc); u.w = pack2(a3.z * hsc, a3.w * hsc);
    *(uint4*)(adst + 8) = u;
    u.x = pack2(b0.x, b0.y); u.y = pack2(b0.z, b0.w);
    u.z = pack2(b1.x, b1.y); u.w = pack2(b1.z, b1.w);
    *(uint4*)bdst = u;
    u.x = pack2(b2.x, b2.y); u.y = pack2(b2.z, b2.w);
    u.z = pack2(b3.x, b3.y); u.w = pack2(b3.z, b3.w);
    *(uint4*)(bdst + 8) = u;
    __syncthreads();
    bf16x8 af[4], bfr[4];
#pragma unroll
    for (int mt = 0; mt < 4; mt++)
      af[mt] = *(const bf16x8*)(As + (wm + mt * 16 + fr) * 40 + koff);
#pragma unroll
    for (int nt = 0; nt < 4; nt++)
      bfr[nt] = *(const bf16x8*)(Bs + (wn + nt * 16 + fr) * 40 + koff);
#pragma unroll
    for (int mt = 0; mt < 4; mt++)
#pragma unroll
      for (int nt = 0; nt < 4; nt++)
        acc[mt][nt] = __builtin_amdgcn_mfma_f32_16x16x32_bf16(af[mt], bfr[nt], acc[mt][nt], 0, 0, 0);
  }
  const int crow = (lane >> 4) * 4;
  const int ccol = et * 128 + fr;
#pragma unroll
  for (int mt = 0; mt < 4; mt++)
#pragma unroll
    for (int nt = 0; nt < 4; nt++)
#pragma unroll
      for (int q = 0; q < 4; q++)
        atomicAdd(&out[(wm + mt * 16 + crow + q) * 1024 + ccol + wn + nt * 16], acc[mt][nt][q]);
}

// ============ score = sigmoid(-dot(mem4, tail)) =================================
__global__ __launch_bounds__(256) void score_kernel(
    const float* __restrict__ x, const float* __restrict__ mem4,
    float* __restrict__ out) {
  __shared__ float red[4];
  const int b = blockIdx.x, tid = threadIdx.x;
  float s = 0.f;
  for (int e = tid; e < E_; e += 256)
    s += mem4[b * E_ + e] * x[b * IN_ + R_ + E_ + e];
  s = wred_sum(s);
  if ((tid & 63) == 0) red[tid >> 6] = s;
  __syncthreads();
  if (tid == 0) {
    float t = red[0] + red[1] + red[2] + red[3];
    out[b] = 1.f / (1.f + expf(t));   // sigmoid(-t)
  }
}

extern "C" void kernel_launch(void* const* d_in, const int* in_sizes, int n_in,
                              void* d_out, int out_size, void* d_ws, size_t ws_size,
                              hipStream_t stream) {
  const float* x    = (const float*)d_in[0];
  const float* kb   = (const float*)d_in[1];
  const float* Wih0 = (const float*)d_in[2];
  const float* Whh0 = (const float*)d_in[3];
  const float* bih0 = (const float*)d_in[4];
  const float* bhh0 = (const float*)d_in[5];
  const float* Wih  = (const float*)d_in[6];
  const float* Whh  = (const float*)d_in[7];
  const float* bih  = (const float*)d_in[8];
  const float* bhh  = (const float*)d_in[9];

  float* ws    = (float*)d_ws;
  float* h2    = ws;                    // 32768
  float* att   = ws + 32768;            // 2048
  float* mem   = ws + 34816;            // 4*131072
  float* prevb = ws + 559104;           // 131072 (bf16 or fp32 prev)
  float* part  = ws + 690176;           // 64*131072 = 8388608
  float* kbbf  = ws + 9078784;          // 33554432 (64Mi bf16)
  const size_t need_big = (size_t)(9078784 + 33554432) * sizeof(float);  // ~170.5 MB
  const bool big = ws_size >= need_big;

  if (big) {
    head_kernel<<<8320, 256, 0, stream>>>(x, kb, Wih0, Whh0, bih0, bhh0,
                                          Wih, Whh, bih, bhh,
                                          (unsigned short*)kbbf, h2, att,
                                          (unsigned short*)prevb);
    for (int i = 0; i < 4; i++) {
      gemm_bf_kernel<<<dim3(8, 64), 256, 0, stream>>>(
          (const unsigned short*)prevb, (const unsigned short*)kbbf, part);
      mid_kernel<<<512, 256, 0, stream>>>(part, h2, att, x, mem,
                                          (unsigned short*)prevb, i);
    }
  } else {
    head_kernel<<<128, 256, 0, stream>>>(x, kb, Wih0, Whh0, bih0, bhh0,
                                         Wih, Whh, bih, bhh,
                                         (unsigned short*)prevb /*unused*/, h2, att,
                                         (unsigned short*)prevb);
    for (int i = 0; i < 4; i++) {
      float* newmem = mem + i * (B_ * E_);
      prep_fp32_kernel<<<512, 256, 0, stream>>>(x, att, mem, prevb, newmem, i);
      gemm_fp32_kernel<<<dim3(8, 64), 256, 0, stream>>>(prevb, h2 + i * (B_ * R_), kb, newmem);
    }
  }
  score_kernel<<<128, 256, 0, stream>>>(x, mem + 3 * (B_ * E_), (float*)d_out);
}

// Round 4
// 627.447 us; speedup vs baseline: 1.1922x; 1.1922x over previous
//
#include <hip/hip_runtime.h>
#include <cstdint>
#include <cstddef>

#define B_ 128
#define E_ 1024
#define R_ 64
#define T_ 4
#define IN_ 2112
#define G_ 256   // 4*R

typedef __attribute__((ext_vector_type(4))) float f32x4;
typedef __attribute__((ext_vector_type(8))) __bf16 bf16x8;

__device__ __forceinline__ unsigned short f2bf(float f) {
  unsigned int u = __float_as_uint(f);
  u += 0x7fffu + ((u >> 16) & 1u);   // RNE
  return (unsigned short)(u >> 16);
}
__device__ __forceinline__ unsigned int pack2(float lo, float hi) {
  return (unsigned int)f2bf(lo) | ((unsigned int)f2bf(hi) << 16);
}
__device__ __forceinline__ float wred_sum(float v) {
#pragma unroll
  for (int m = 32; m > 0; m >>= 1) v += __shfl_xor(v, m, 64);
  return v;
}
__device__ __forceinline__ float wred_max(float v) {
#pragma unroll
  for (int m = 32; m > 0; m >>= 1) v = fmaxf(v, __shfl_xor(v, m, 64));
  return v;
}
__device__ __forceinline__ float sigmoidf_(float x) { return 1.f / (1.f + expf(-x)); }
// fast gates: v_exp/v_rcp based; exact enough (output saturates), monotone, no branches
__device__ __forceinline__ float fast_sig(float x) {
  return __builtin_amdgcn_rcpf(1.f + __expf(-x));
}
__device__ __forceinline__ float fast_tanh(float x) {
  return 1.f - 2.f * __builtin_amdgcn_rcpf(1.f + __expf(2.f * x));
}

__device__ __forceinline__ void gload_lds16(const void* g, void* l) {
  __builtin_amdgcn_global_load_lds(
      (const __attribute__((address_space(1))) unsigned int*)g,
      (__attribute__((address_space(3))) unsigned int*)l, 16, 0, 0);
}

// ============ head: blocks [0,128) = LSTM recurrence; blocks >=128 = kb
//              fp32->bf16 conversion (overlapped under the LSTM).
__global__ __launch_bounds__(256, 2) void head_kernel(
    const float* __restrict__ x, const float* __restrict__ kb,
    const float* __restrict__ Wih0, const float* __restrict__ Whh0,
    const float* __restrict__ bih0, const float* __restrict__ bhh0,
    const float* __restrict__ Wih, const float* __restrict__ Whh,
    const float* __restrict__ bih, const float* __restrict__ bhh,
    unsigned short* __restrict__ kb_bf,
    float* __restrict__ h2_out, float* __restrict__ att_out,
    unsigned short* __restrict__ prev_bf) {
  const int tid = threadIdx.x;

  if (blockIdx.x >= 128) {
    // ---- kb conversion: 64Mi elems over 8192 blocks, 32 elems/thread ----
    const size_t base = (size_t)(blockIdx.x - 128) * 8192;
#pragma unroll
    for (int c = 0; c < 4; c++) {
      size_t o = base + (size_t)c * 2048 + (size_t)tid * 8;
      float4 v0 = *(const float4*)(kb + o);
      float4 v1 = *(const float4*)(kb + o + 4);
      uint4 u;
      u.x = pack2(v0.x, v0.y); u.y = pack2(v0.z, v0.w);
      u.z = pack2(v1.x, v1.y); u.w = pack2(v1.z, v1.w);
      *(uint4*)(kb_bf + o) = u;
    }
    return;
  }

  __shared__ __align__(16) float xrow[IN_];
  __shared__ __align__(16) float pre_lds[G_];
  __shared__ __align__(16) float hbuf[R_];
  __shared__ __align__(16) float zbuf[2][G_];
  __shared__ __align__(16) float hs_out[T_][R_];
  __shared__ __align__(16) float hmat[T_][R_];

  const int b = blockIdx.x;
  const int lane = tid & 63, wv = tid >> 6;
  const int s = tid & 63;

  // ---- stage x row ----
  for (int l = tid; l < IN_; l += 256) xrow[l] = x[b * IN_ + l];
  __syncthreads();

  // ---- pre0, COALESCED: wave wv computes outputs g in [wv*64, wv*64+64).
  //      For each g, 64 lanes read Wih0[g][..] contiguously (1KB/instr, full
  //      line use) and shuffle-reduce. Was: per-thread strided rows (8448B
  //      lane stride, 16B-of-64B line use, latency-bound under conv traffic).
  {
    const int gbase = wv * 64;
#pragma unroll 2
    for (int gg = 0; gg < 64; gg++) {
      const float* wr = Wih0 + (size_t)(gbase + gg) * IN_;
      float4 s4 = {0.f, 0.f, 0.f, 0.f};
#pragma unroll
      for (int k = 0; k < 8; k++) {
        float4 w = *(const float4*)(wr + (lane + 64 * k) * 4);
        float4 xv = *(const float4*)(&xrow[(lane + 64 * k) * 4]);
        s4.x += w.x * xv.x; s4.y += w.y * xv.y;
        s4.z += w.z * xv.z; s4.w += w.w * xv.w;
      }
      float part = (s4.x + s4.y) + (s4.z + s4.w);
      part += wr[2048 + lane] * xrow[2048 + lane];   // tail cols 2048..2111
      float tot = wred_sum(part);
      if (lane == 0) pre_lds[gbase + gg] = tot;
    }
  }
  // wave-local write->read: compiler inserts lgkmcnt wait; no barrier needed
  float p0 = pre_lds[tid] + bih0[tid] + bhh0[tid];

  float4 w4[16];   // 64 VGPRs: this thread's weight row (Whh or Wih), reg-cached
  float pret[T_];

  // scan over T_ steps; W row must already be in w4; pret[] precomputed.
  // One barrier per step; gates computed redundantly by all 4 waves.
  auto scan = [&]() {
    __syncthreads();                 // prior-layer gate writes fully done
    hbuf[s] = 0.f;                   // each wave zeroes all 64 (redundant, own-copy)
    float creg = 0.f;
#pragma unroll
    for (int t = 0; t < T_; t++) {
      float z0 = pret[t], z1 = 0.f, z2 = 0.f, z3 = 0.f;
#pragma unroll
      for (int q = 0; q < 16; q += 4) {
        float4 h0 = *(const float4*)(&hbuf[q * 4]);
        float4 h1 = *(const float4*)(&hbuf[q * 4 + 4]);
        float4 h2v = *(const float4*)(&hbuf[q * 4 + 8]);
        float4 h3 = *(const float4*)(&hbuf[q * 4 + 12]);
        z0 += h0.x * w4[q].x + h0.y * w4[q].y + h0.z * w4[q].z + h0.w * w4[q].w;
        z1 += h1.x * w4[q + 1].x + h1.y * w4[q + 1].y + h1.z * w4[q + 1].z + h1.w * w4[q + 1].w;
        z2 += h2v.x * w4[q + 2].x + h2v.y * w4[q + 2].y + h2v.z * w4[q + 2].z + h2v.w * w4[q + 2].w;
        z3 += h3.x * w4[q + 3].x + h3.y * w4[q + 3].y + h3.z * w4[q + 3].z + h3.w * w4[q + 3].w;
      }
      zbuf[t & 1][tid] = (z0 + z1) + (z2 + z3);
      __syncthreads();
      float iv = fast_sig(zbuf[t & 1][s]);
      float fv = fast_sig(zbuf[t & 1][R_ + s]);
      float gv = fast_tanh(zbuf[t & 1][2 * R_ + s]);
      float ov = fast_sig(zbuf[t & 1][3 * R_ + s]);
      creg = fv * creg + iv * gv;
      float h = ov * fast_tanh(creg);
      hbuf[s] = h;                   // redundant identical writes across waves
      hs_out[t][s] = h;
    }
  };

  // ---- layer 0 ----
#pragma unroll
  for (int t = 0; t < T_; t++) pret[t] = p0;
#pragma unroll
  for (int q = 0; q < 16; q++)
    w4[q] = *(const float4*)(Whh0 + (size_t)tid * R_ + q * 4);
  scan();

  // ---- layers 1..3 ----
  for (int l = 0; l < T_ - 1; l++) {
#pragma unroll
    for (int q = 0; q < 16; q++)
      w4[q] = *(const float4*)(Wih + ((size_t)l * G_ + tid) * R_ + q * 4);
    const float bsum = bih[l * G_ + tid] + bhh[l * G_ + tid];
#pragma unroll
    for (int t = 0; t < T_; t++) {
      float p = bsum;
#pragma unroll
      for (int q = 0; q < 16; q++) {
        float4 hv = *(const float4*)(&hs_out[t][q * 4]);
        p += hv.x * w4[q].x + hv.y * w4[q].y + hv.z * w4[q].z + hv.w * w4[q].w;
      }
      pret[t] = p;
    }
#pragma unroll
    for (int q = 0; q < 16; q++)
      w4[q] = *(const float4*)(Whh + ((size_t)l * G_ + tid) * R_ + q * 4);
    scan();
  }

  // ---- softmax head: wave wv handles timestep t = wv ----
  {
    float v = hs_out[wv][lane];
    float mx = wred_max(v);
    float ev = expf(v - mx);
    float sm = wred_sum(ev);
    float hval = ev / sm;                 // h = softmax(hs)
    hmat[wv][lane] = hval;
    float mx2 = wred_max(hval);
    float e2 = expf(hval - mx2);
    float s2 = wred_sum(e2);
    h2_out[(wv * B_ + b) * R_ + lane] = e2 / s2;   // h2 = softmax(h)
    __syncthreads();
    float dots[T_];
    for (int k = 0; k <= wv; k++)
      dots[k] = wred_sum(hmat[k][lane] * hmat[wv][lane]);
    if (lane == 0) {
      float mx3 = dots[0];
      for (int k = 1; k <= wv; k++) mx3 = fmaxf(mx3, dots[k]);
      float ss = 0.f, es[T_];
      for (int k = 0; k <= wv; k++) { es[k] = expf(dots[k] - mx3); ss += es[k]; }
      for (int k = 0; k <= wv; k++) att_out[(wv * B_ + b) * 4 + k] = es[k] / ss;
    }
  }

  // ---- fused prep0: att[0,b,0] == 1.0 exactly, so prev0 = bf16(x[b, R:R+E]) ----
  for (int l = tid; l < E_; l += 256)
    prev_bf[b * E_ + l] = f2bf(xrow[R_ + l]);
}

// ============ GEMM: part[r][b][e] = sum_f prev[b,f]*kb[r,e,f]  (bf16 MFMA) =======
// grid (8 e-tiles, 64 r), block 256. Tile 128x128, K=1024.
// 2-phase pipeline: prefetch next K-tile via global_load_lds before MFMA of
// current, single barrier per K-step. (r2-proven version.)
__global__ __launch_bounds__(256) void gemm_bf_kernel(
    const unsigned short* __restrict__ Abf,   // [128][1024] bf16
    const unsigned short* __restrict__ Kbf,   // [64][1024][1024] bf16
    float* __restrict__ part) {               // [64][128][1024]
  __shared__ unsigned short As[2][128 * 32];
  __shared__ unsigned short Bs[2][128 * 32];
  const int tid = threadIdx.x, wv = tid >> 6, lane = tid & 63;
  const int et = blockIdx.x, r = blockIdx.y;
  const int wm = (wv & 1) * 64, wn = (wv >> 1) * 64;
  const int fr = lane & 15, koff = (lane >> 4) * 8;

  // staging: wave wv covers rows [wv*32, wv*32+32), two 16-row instructions each
  const int srow = wv * 32 + (lane >> 2);
  const int scol = (lane & 3) * 8;
  const unsigned short* agp = Abf + (size_t)srow * 1024 + scol;
  const unsigned short* bgp = Kbf + (size_t)r * 1048576 + (size_t)(et * 128 + srow) * 1024 + scol;

  f32x4 acc[4][4];
#pragma unroll
  for (int mt = 0; mt < 4; mt++)
#pragma unroll
    for (int nt = 0; nt < 4; nt++)
#pragma unroll
      for (int q = 0; q < 4; q++) acc[mt][nt][q] = 0.f;

  auto stage = [&](int buf, int kk) {
    gload_lds16(agp + kk * 32,             As[buf] + wv * 1024);
    gload_lds16(agp + kk * 32 + 16 * 1024, As[buf] + wv * 1024 + 512);
    gload_lds16(bgp + kk * 32,             Bs[buf] + wv * 1024);
    gload_lds16(bgp + kk * 32 + 16 * 1024, Bs[buf] + wv * 1024 + 512);
  };

  stage(0, 0);
  __syncthreads();   // tile 0 resident
  int cur = 0;
  for (int kk = 0; kk < 32; kk++) {
    if (kk < 31) stage(cur ^ 1, kk + 1);   // issue next-tile loads early
    bf16x8 af[4], bfr[4];
#pragma unroll
    for (int mt = 0; mt < 4; mt++)
      af[mt] = *(const bf16x8*)(As[cur] + (wm + mt * 16 + fr) * 32 + koff);
#pragma unroll
    for (int nt = 0; nt < 4; nt++)
      bfr[nt] = *(const bf16x8*)(Bs[cur] + (wn + nt * 16 + fr) * 32 + koff);
#pragma unroll
    for (int mt = 0; mt < 4; mt++)
#pragma unroll
      for (int nt = 0; nt < 4; nt++)
        acc[mt][nt] = __builtin_amdgcn_mfma_f32_16x16x32_bf16(af[mt], bfr[nt], acc[mt][nt], 0, 0, 0);
    __syncthreads();   // drains prefetch (vmcnt) + frag reads (lgkm); flip
    cur ^= 1;
  }
  // C/D: col = lane&15, row = (lane>>4)*4 + q
  const int crow = (lane >> 4) * 4;
  float* pout = part + (size_t)r * 131072;
#pragma unroll
  for (int mt = 0; mt < 4; mt++)
#pragma unroll
    for (int nt = 0; nt < 4; nt++)
#pragma unroll
      for (int q = 0; q < 4; q++)
        pout[(wm + mt * 16 + crow + q) * 1024 + et * 128 + wn + nt * 16 + fr] = acc[mt][nt][q];
}

// ============ mid: mem_it = sum_r h2[it,b,r]*part[r,b,e]; prep next prev ========
__global__ __launch_bounds__(256) void mid_kernel(
    const float* __restrict__ part, const float* __restrict__ h2,
    const float* __restrict__ att, const float* __restrict__ x,
    float* __restrict__ mem, unsigned short* __restrict__ prev_bf, int it) {
  const int idx = blockIdx.x * 256 + threadIdx.x;   // 131072
  const int b = idx >> 10, e = idx & 1023;
  const float* h2row = h2 + (it * B_ + b) * R_;     // b uniform per block
  const float* pp = part + idx;
  float s = 0.f;
#pragma unroll 8
  for (int rr = 0; rr < 64; rr++) s += h2row[rr] * pp[(size_t)rr * 131072];
  mem[it * 131072 + idx] = s;
  if (it < 3) {
    const float* arow = att + ((it + 1) * B_ + b) * 4;
    float acc = arow[0] * x[b * IN_ + R_ + e];
    for (int k = 1; k <= it; k++) acc += arow[k] * mem[(k - 1) * 131072 + idx];
    acc += arow[it + 1] * s;
    prev_bf[idx] = f2bf(acc);
  }
}

// ============ fallback path (small ws): round-0 fp32-kb gemm ====================
__global__ __launch_bounds__(256) void prep_fp32_kernel(
    const float* __restrict__ x, const float* __restrict__ att,
    const float* __restrict__ mem, float* __restrict__ prev,
    float* __restrict__ newmem, int it) {
  const int idx = blockIdx.x * 256 + threadIdx.x;
  const int b = idx >> 10, e = idx & 1023;
  const float* arow = att + (it * B_ + b) * 4;
  float acc = arow[0] * x[b * IN_ + R_ + e];
  for (int k = 1; k <= it; k++)
    acc += arow[k] * mem[(k - 1) * (B_ * E_) + b * E_ + e];
  prev[idx] = acc;
  newmem[idx] = 0.f;
}

__global__ __launch_bounds__(256) void gemm_fp32_kernel(
    const float* __restrict__ prev, const float* __restrict__ h2,
    const float* __restrict__ kb, float* __restrict__ out) {
  __shared__ unsigned short As[128 * 40];
  __shared__ unsigned short Bs[128 * 40];
  __shared__ float h2s[128];
  const int tid = threadIdx.x;
  const int et = blockIdx.x;
  const int r = blockIdx.y;
  if (tid < 128) h2s[tid] = h2[tid * 64 + r];
  __syncthreads();
  const int row = tid >> 1;
  const int c0 = (tid & 1) * 16;
  const float hsc = h2s[row];
  const float* aptr = prev + row * 1024 + c0;
  const float* bptr = kb + (size_t)r * (1024u * 1024u) + (size_t)(et * 128 + row) * 1024 + c0;
  unsigned short* adst = As + row * 40 + c0;
  unsigned short* bdst = Bs + row * 40 + c0;
  const int wv = tid >> 6, lane = tid & 63;
  const int wm = (wv & 1) * 64, wn = (wv >> 1) * 64;
  const int fr = lane & 15, koff = (lane >> 4) * 8;
  f32x4 acc[4][4];
#pragma unroll
  for (int mt = 0; mt < 4; mt++)
#pragma unroll
    for (int nt = 0; nt < 4; nt++)
#pragma unroll
      for (int q = 0; q < 4; q++) acc[mt][nt][q] = 0.f;
  for (int kk = 0; kk < 32; kk++) {
    const float4 a0 = *(const float4*)(aptr + kk * 32);
    const float4 a1 = *(const float4*)(aptr + kk * 32 + 4);
    const float4 a2 = *(const float4*)(aptr + kk * 32 + 8);
    const float4 a3 = *(const float4*)(aptr + kk * 32 + 12);
    const float4 b0 = *(const float4*)(bptr + kk * 32);
    const float4 b1 = *(const float4*)(bptr + kk * 32 + 4);
    const float4 b2 = *(const float4*)(bptr + kk * 32 + 8);
    const float4 b3 = *(const float4*)(bptr + kk * 32 + 12);
    __syncthreads();
    uint4 u;
    u.x = pack2(a0.x * hsc, a0.y * hsc); u.y = pack2(a0.z * hsc, a0.w * hsc);
    u.z = pack2(a1.x * hsc, a1.y * hsc); u.w = pack2(a1.z * hsc, a1.w * hsc);
    *(uint4*)adst = u;
    u.x = pack2(a2.x * hsc, a2.y * hsc); u.y = pack2(a2.z * hsc, a2.w * hsc);
    u.z = pack2(a3.x * hsc, a3.y * hsc); u.w = pack2(a3.z * hsc, a3.w * hsc);
    *(uint4*)(adst + 8) = u;
    u.x = pack2(b0.x, b0.y); u.y = pack2(b0.z, b0.w);
    u.z = pack2(b1.x, b1.y); u.w = pack2(b1.z, b1.w);
    *(uint4*)bdst = u;
    u.x = pack2(b2.x, b2.y); u.y = pack2(b2.z, b2.w);
    u.z = pack2(b3.x, b3.y); u.w = pack2(b3.z, b3.w);
    *(uint4*)(bdst + 8) = u;
    __syncthreads();
    bf16x8 af[4], bfr[4];
#pragma unroll
    for (int mt = 0; mt < 4; mt++)
      af[mt] = *(const bf16x8*)(As + (wm + mt * 16 + fr) * 40 + koff);
#pragma unroll
    for (int nt = 0; nt < 4; nt++)
      bfr[nt] = *(const bf16x8*)(Bs + (wn + nt * 16 + fr) * 40 + koff);
#pragma unroll
    for (int mt = 0; mt < 4; mt++)
#pragma unroll
      for (int nt = 0; nt < 4; nt++)
        acc[mt][nt] = __builtin_amdgcn_mfma_f32_16x16x32_bf16(af[mt], bfr[nt], acc[mt][nt], 0, 0, 0);
  }
  const int crow = (lane >> 4) * 4;
  const int ccol = et * 128 + fr;
#pragma unroll
  for (int mt = 0; mt < 4; mt++)
#pragma unroll
    for (int nt = 0; nt < 4; nt++)
#pragma unroll
      for (int q = 0; q < 4; q++)
        atomicAdd(&out[(wm + mt * 16 + crow + q) * 1024 + ccol + wn + nt * 16], acc[mt][nt][q]);
}

// ============ score = sigmoid(-dot(mem4, tail)) =================================
__global__ __launch_bounds__(256) void score_kernel(
    const float* __restrict__ x, const float* __restrict__ mem4,
    float* __restrict__ out) {
  __shared__ float red[4];
  const int b = blockIdx.x, tid = threadIdx.x;
  float s = 0.f;
  for (int e = tid; e < E_; e += 256)
    s += mem4[b * E_ + e] * x[b * IN_ + R_ + E_ + e];
  s = wred_sum(s);
  if ((tid & 63) == 0) red[tid >> 6] = s;
  __syncthreads();
  if (tid == 0) {
    float t = red[0] + red[1] + red[2] + red[3];
    out[b] = 1.f / (1.f + expf(t));   // sigmoid(-t)
  }
}

extern "C" void kernel_launch(void* const* d_in, const int* in_sizes, int n_in,
                              void* d_out, int out_size, void* d_ws, size_t ws_size,
                              hipStream_t stream) {
  const float* x    = (const float*)d_in[0];
  const float* kb   = (const float*)d_in[1];
  const float* Wih0 = (const float*)d_in[2];
  const float* Whh0 = (const float*)d_in[3];
  const float* bih0 = (const float*)d_in[4];
  const float* bhh0 = (const float*)d_in[5];
  const float* Wih  = (const float*)d_in[6];
  const float* Whh  = (const float*)d_in[7];
  const float* bih  = (const float*)d_in[8];
  const float* bhh  = (const float*)d_in[9];

  float* ws    = (float*)d_ws;
  float* h2    = ws;                    // 32768
  float* att   = ws + 32768;            // 2048
  float* mem   = ws + 34816;            // 4*131072
  float* prevb = ws + 559104;           // 131072 (bf16 or fp32 prev)
  float* part  = ws + 690176;           // 64*131072 = 8388608
  float* kbbf  = ws + 9078784;          // 33554432 (64Mi bf16)
  const size_t need_big = (size_t)(9078784 + 33554432) * sizeof(float);  // ~170.5 MB
  const bool big = ws_size >= need_big;

  if (big) {
    head_kernel<<<8320, 256, 0, stream>>>(x, kb, Wih0, Whh0, bih0, bhh0,
                                          Wih, Whh, bih, bhh,
                                          (unsigned short*)kbbf, h2, att,
                                          (unsigned short*)prevb);
    for (int i = 0; i < 4; i++) {
      gemm_bf_kernel<<<dim3(8, 64), 256, 0, stream>>>(
          (const unsigned short*)prevb, (const unsigned short*)kbbf, part);
      mid_kernel<<<512, 256, 0, stream>>>(part, h2, att, x, mem,
                                          (unsigned short*)prevb, i);
    }
  } else {
    head_kernel<<<128, 256, 0, stream>>>(x, kb, Wih0, Whh0, bih0, bhh0,
                                         Wih, Whh, bih, bhh,
                                         (unsigned short*)prevb /*unused*/, h2, att,
                                         (unsigned short*)prevb);
    for (int i = 0; i < 4; i++) {
      float* newmem = mem + i * (B_ * E_);
      prep_fp32_kernel<<<512, 256, 0, stream>>>(x, att, mem, prevb, newmem, i);
      gemm_fp32_kernel<<<dim3(8, 64), 256, 0, stream>>>(prevb, h2 + i * (B_ * R_), kb, newmem);
    }
  }
  score_kernel<<<128, 256, 0, stream>>>(x, mem + 3 * (B_ * E_), (float*)d_out);
}

// Round 5
// 609.361 us; speedup vs baseline: 1.2276x; 1.0297x over previous
//
#include <hip/hip_runtime.h>
#include <cstdint>
#include <cstddef>

#define B_ 128
#define E_ 1024
#define R_ 64
#define T_ 4
#define IN_ 2112
#define G_ 256   // 4*R

typedef __attribute__((ext_vector_type(4))) float f32x4;
typedef __attribute__((ext_vector_type(8))) __bf16 bf16x8;

__device__ __forceinline__ unsigned short f2bf(float f) {
  unsigned int u = __float_as_uint(f);
  u += 0x7fffu + ((u >> 16) & 1u);   // RNE
  return (unsigned short)(u >> 16);
}
__device__ __forceinline__ unsigned int pack2(float lo, float hi) {
  return (unsigned int)f2bf(lo) | ((unsigned int)f2bf(hi) << 16);
}
__device__ __forceinline__ float wred_sum(float v) {
#pragma unroll
  for (int m = 32; m > 0; m >>= 1) v += __shfl_xor(v, m, 64);
  return v;
}
__device__ __forceinline__ float wred_max(float v) {
#pragma unroll
  for (int m = 32; m > 0; m >>= 1) v = fmaxf(v, __shfl_xor(v, m, 64));
  return v;
}
__device__ __forceinline__ float fast_sig(float x) {
  return __builtin_amdgcn_rcpf(1.f + __expf(-x));
}
__device__ __forceinline__ float fast_tanh(float x) {
  return 1.f - 2.f * __builtin_amdgcn_rcpf(1.f + __expf(2.f * x));
}

__device__ __forceinline__ void gload_lds16(const void* g, void* l) {
  __builtin_amdgcn_global_load_lds(
      (const __attribute__((address_space(1))) unsigned int*)g,
      (__attribute__((address_space(3))) unsigned int*)l, 16, 0, 0);
}

// ============ fused0: blocks [0,128) = LSTM recurrence + softmax head;
//              blocks [128,640) = round-0 GEMM reading kb in FP32, converting
//              in-register, side-writing kbbf (bf16) exactly once per element.
//              No conversion pass needed; LSTM hides under the GEMM.
__global__ __launch_bounds__(256) void fused0_kernel(
    const float* __restrict__ x, const float* __restrict__ kb,
    const float* __restrict__ Wih0, const float* __restrict__ Whh0,
    const float* __restrict__ bih0, const float* __restrict__ bhh0,
    const float* __restrict__ Wih, const float* __restrict__ Whh,
    const float* __restrict__ bih, const float* __restrict__ bhh,
    unsigned short* __restrict__ kb_bf,
    float* __restrict__ part,
    float* __restrict__ h2_out, float* __restrict__ att_out) {
  __shared__ __align__(16) unsigned char smem[20480];
  const int tid = threadIdx.x;
  const int bid = blockIdx.x;

  if (bid >= 128) {
    // ---------------- round-0 GEMM: part[r][b][e] = sum_f A[b,f]*kb[r,e,f]
    //  A[b,f] = f2bf(x[b, 64+f])  (att[0,b,0]==1.0 exactly)
    //  B staged fp32->bf16 in LDS; bf16 also stored to kb_bf (exactly once).
    unsigned short* As = (unsigned short*)smem;          // [128][40]
    unsigned short* Bs = As + 128 * 40;                  // [128][40]
    const int g = bid - 128;
    const int et = g & 7, r = g >> 3;
    const int row = tid >> 1;
    const int c0 = (tid & 1) * 16;
    const float* aptr = x + (size_t)row * IN_ + R_ + c0;
    const float* bptr = kb + (size_t)r * 1048576 + (size_t)(et * 128 + row) * 1024 + c0;
    unsigned short* kdst = kb_bf + (size_t)r * 1048576 + (size_t)(et * 128 + row) * 1024 + c0;
    unsigned short* adst = As + row * 40 + c0;
    unsigned short* bdst = Bs + row * 40 + c0;
    const int wv = tid >> 6, lane = tid & 63;
    const int wm = (wv & 1) * 64, wn = (wv >> 1) * 64;
    const int fr = lane & 15, koff = (lane >> 4) * 8;
    f32x4 acc[4][4];
#pragma unroll
    for (int mt = 0; mt < 4; mt++)
#pragma unroll
      for (int nt = 0; nt < 4; nt++)
#pragma unroll
        for (int q = 0; q < 4; q++) acc[mt][nt][q] = 0.f;

    for (int kk = 0; kk < 32; kk++) {
      const float4 a0 = *(const float4*)(aptr + kk * 32);
      const float4 a1 = *(const float4*)(aptr + kk * 32 + 4);
      const float4 a2 = *(const float4*)(aptr + kk * 32 + 8);
      const float4 a3 = *(const float4*)(aptr + kk * 32 + 12);
      const float4 b0 = *(const float4*)(bptr + kk * 32);
      const float4 b1 = *(const float4*)(bptr + kk * 32 + 4);
      const float4 b2 = *(const float4*)(bptr + kk * 32 + 8);
      const float4 b3 = *(const float4*)(bptr + kk * 32 + 12);
      __syncthreads();   // prior frag reads done before LDS overwrite
      uint4 u;
      u.x = pack2(a0.x, a0.y); u.y = pack2(a0.z, a0.w);
      u.z = pack2(a1.x, a1.y); u.w = pack2(a1.z, a1.w);
      *(uint4*)adst = u;
      u.x = pack2(a2.x, a2.y); u.y = pack2(a2.z, a2.w);
      u.z = pack2(a3.x, a3.y); u.w = pack2(a3.z, a3.w);
      *(uint4*)(adst + 8) = u;
      uint4 ub;
      ub.x = pack2(b0.x, b0.y); ub.y = pack2(b0.z, b0.w);
      ub.z = pack2(b1.x, b1.y); ub.w = pack2(b1.z, b1.w);
      *(uint4*)bdst = ub;
      *(uint4*)(kdst + kk * 32) = ub;        // side-write bf16 kb (cols kk*32+c0..+8)
      ub.x = pack2(b2.x, b2.y); ub.y = pack2(b2.z, b2.w);
      ub.z = pack2(b3.x, b3.y); ub.w = pack2(b3.z, b3.w);
      *(uint4*)(bdst + 8) = ub;
      *(uint4*)(kdst + kk * 32 + 8) = ub;    // cols kk*32+c0+8..+16
      __syncthreads();   // tiles resident
      bf16x8 af[4], bfr[4];
#pragma unroll
      for (int mt = 0; mt < 4; mt++)
        af[mt] = *(const bf16x8*)(As + (wm + mt * 16 + fr) * 40 + koff);
#pragma unroll
      for (int nt = 0; nt < 4; nt++)
        bfr[nt] = *(const bf16x8*)(Bs + (wn + nt * 16 + fr) * 40 + koff);
#pragma unroll
      for (int mt = 0; mt < 4; mt++)
#pragma unroll
        for (int nt = 0; nt < 4; nt++)
          acc[mt][nt] = __builtin_amdgcn_mfma_f32_16x16x32_bf16(af[mt], bfr[nt], acc[mt][nt], 0, 0, 0);
    }
    const int crow = (lane >> 4) * 4;
    float* pout = part + (size_t)r * 131072;
#pragma unroll
    for (int mt = 0; mt < 4; mt++)
#pragma unroll
      for (int nt = 0; nt < 4; nt++)
#pragma unroll
        for (int q = 0; q < 4; q++)
          pout[(wm + mt * 16 + crow + q) * 1024 + et * 128 + wn + nt * 16 + fr] = acc[mt][nt][q];
    return;
  }

  // ---------------- LSTM branch (b = bid) ----------------
  float* xrow    = (float*)smem;            // 2112
  float* pre_lds = xrow + IN_;              // 256
  float* hbuf    = pre_lds + G_;            // 64
  float* zbuf    = hbuf + R_;               // 2*256
  float* hs_out  = zbuf + 2 * G_;           // 4*64
  float* hmat    = hs_out + T_ * R_;        // 4*64

  const int b = bid;
  const int lane = tid & 63, wv = tid >> 6;
  const int s = tid & 63;

  for (int l = tid; l < IN_; l += 256) xrow[l] = x[b * IN_ + l];
  __syncthreads();

  // pre0, coalesced: wave wv computes outputs g in [wv*64, wv*64+64)
  {
    const int gbase = wv * 64;
#pragma unroll 2
    for (int gg = 0; gg < 64; gg++) {
      const float* wr = Wih0 + (size_t)(gbase + gg) * IN_;
      float4 s4 = {0.f, 0.f, 0.f, 0.f};
#pragma unroll
      for (int k = 0; k < 8; k++) {
        float4 w = *(const float4*)(wr + (lane + 64 * k) * 4);
        float4 xv = *(const float4*)(&xrow[(lane + 64 * k) * 4]);
        s4.x += w.x * xv.x; s4.y += w.y * xv.y;
        s4.z += w.z * xv.z; s4.w += w.w * xv.w;
      }
      float part_ = (s4.x + s4.y) + (s4.z + s4.w);
      part_ += wr[2048 + lane] * xrow[2048 + lane];
      float tot = wred_sum(part_);
      if (lane == 0) pre_lds[gbase + gg] = tot;
    }
  }
  float p0 = pre_lds[tid] + bih0[tid] + bhh0[tid];

  float4 w4[16];
  float pret[T_];

  auto scan = [&]() {
    __syncthreads();
    hbuf[s] = 0.f;
    float creg = 0.f;
#pragma unroll
    for (int t = 0; t < T_; t++) {
      float z0 = pret[t], z1 = 0.f, z2 = 0.f, z3 = 0.f;
#pragma unroll
      for (int q = 0; q < 16; q += 4) {
        float4 h0 = *(const float4*)(&hbuf[q * 4]);
        float4 h1 = *(const float4*)(&hbuf[q * 4 + 4]);
        float4 h2v = *(const float4*)(&hbuf[q * 4 + 8]);
        float4 h3 = *(const float4*)(&hbuf[q * 4 + 12]);
        z0 += h0.x * w4[q].x + h0.y * w4[q].y + h0.z * w4[q].z + h0.w * w4[q].w;
        z1 += h1.x * w4[q + 1].x + h1.y * w4[q + 1].y + h1.z * w4[q + 1].z + h1.w * w4[q + 1].w;
        z2 += h2v.x * w4[q + 2].x + h2v.y * w4[q + 2].y + h2v.z * w4[q + 2].z + h2v.w * w4[q + 2].w;
        z3 += h3.x * w4[q + 3].x + h3.y * w4[q + 3].y + h3.z * w4[q + 3].z + h3.w * w4[q + 3].w;
      }
      zbuf[(t & 1) * G_ + tid] = (z0 + z1) + (z2 + z3);
      __syncthreads();
      float iv = fast_sig(zbuf[(t & 1) * G_ + s]);
      float fv = fast_sig(zbuf[(t & 1) * G_ + R_ + s]);
      float gv = fast_tanh(zbuf[(t & 1) * G_ + 2 * R_ + s]);
      float ov = fast_sig(zbuf[(t & 1) * G_ + 3 * R_ + s]);
      creg = fv * creg + iv * gv;
      float h = ov * fast_tanh(creg);
      hbuf[s] = h;
      hs_out[t * R_ + s] = h;
    }
  };

  // layer 0
#pragma unroll
  for (int t = 0; t < T_; t++) pret[t] = p0;
#pragma unroll
  for (int q = 0; q < 16; q++)
    w4[q] = *(const float4*)(Whh0 + (size_t)tid * R_ + q * 4);
  scan();

  // layers 1..3
  for (int l = 0; l < T_ - 1; l++) {
#pragma unroll
    for (int q = 0; q < 16; q++)
      w4[q] = *(const float4*)(Wih + ((size_t)l * G_ + tid) * R_ + q * 4);
    const float bsum = bih[l * G_ + tid] + bhh[l * G_ + tid];
#pragma unroll
    for (int t = 0; t < T_; t++) {
      float p = bsum;
#pragma unroll
      for (int q = 0; q < 16; q++) {
        float4 hv = *(const float4*)(&hs_out[t * R_ + q * 4]);
        p += hv.x * w4[q].x + hv.y * w4[q].y + hv.z * w4[q].z + hv.w * w4[q].w;
      }
      pret[t] = p;
    }
#pragma unroll
    for (int q = 0; q < 16; q++)
      w4[q] = *(const float4*)(Whh + ((size_t)l * G_ + tid) * R_ + q * 4);
    scan();
  }

  // softmax head: wave wv handles timestep t = wv
  {
    float v = hs_out[wv * R_ + lane];
    float mx = wred_max(v);
    float ev = expf(v - mx);
    float sm = wred_sum(ev);
    float hval = ev / sm;                 // h = softmax(hs)
    hmat[wv * R_ + lane] = hval;
    float mx2 = wred_max(hval);
    float e2 = expf(hval - mx2);
    float s2 = wred_sum(e2);
    h2_out[(wv * B_ + b) * R_ + lane] = e2 / s2;   // h2 = softmax(h)
    __syncthreads();
    float dots[T_];
    for (int k = 0; k <= wv; k++)
      dots[k] = wred_sum(hmat[k * R_ + lane] * hmat[wv * R_ + lane]);
    if (lane == 0) {
      float mx3 = dots[0];
      for (int k = 1; k <= wv; k++) mx3 = fmaxf(mx3, dots[k]);
      float ss = 0.f, es[T_];
      for (int k = 0; k <= wv; k++) { es[k] = expf(dots[k] - mx3); ss += es[k]; }
      for (int k = 0; k <= wv; k++) att_out[(wv * B_ + b) * 4 + k] = es[k] / ss;
    }
  }
}

// ============ GEMM rounds 1-3: part[r][b][e] = sum_f prev[b,f]*kb[r,e,f] =======
// grid (8 e-tiles, 64 r), block 256. Tile 128x128, K=1024.
// 2-phase pipeline: prefetch next K-tile via global_load_lds before MFMA of
// current, single barrier per K-step. (r2-proven version.)
__global__ __launch_bounds__(256) void gemm_bf_kernel(
    const unsigned short* __restrict__ Abf,   // [128][1024] bf16
    const unsigned short* __restrict__ Kbf,   // [64][1024][1024] bf16
    float* __restrict__ part) {               // [64][128][1024]
  __shared__ unsigned short As[2][128 * 32];
  __shared__ unsigned short Bs[2][128 * 32];
  const int tid = threadIdx.x, wv = tid >> 6, lane = tid & 63;
  const int et = blockIdx.x, r = blockIdx.y;
  const int wm = (wv & 1) * 64, wn = (wv >> 1) * 64;
  const int fr = lane & 15, koff = (lane >> 4) * 8;

  const int srow = wv * 32 + (lane >> 2);
  const int scol = (lane & 3) * 8;
  const unsigned short* agp = Abf + (size_t)srow * 1024 + scol;
  const unsigned short* bgp = Kbf + (size_t)r * 1048576 + (size_t)(et * 128 + srow) * 1024 + scol;

  f32x4 acc[4][4];
#pragma unroll
  for (int mt = 0; mt < 4; mt++)
#pragma unroll
    for (int nt = 0; nt < 4; nt++)
#pragma unroll
      for (int q = 0; q < 4; q++) acc[mt][nt][q] = 0.f;

  auto stage = [&](int buf, int kk) {
    gload_lds16(agp + kk * 32,             As[buf] + wv * 1024);
    gload_lds16(agp + kk * 32 + 16 * 1024, As[buf] + wv * 1024 + 512);
    gload_lds16(bgp + kk * 32,             Bs[buf] + wv * 1024);
    gload_lds16(bgp + kk * 32 + 16 * 1024, Bs[buf] + wv * 1024 + 512);
  };

  stage(0, 0);
  __syncthreads();   // tile 0 resident
  int cur = 0;
  for (int kk = 0; kk < 32; kk++) {
    if (kk < 31) stage(cur ^ 1, kk + 1);   // issue next-tile loads early
    bf16x8 af[4], bfr[4];
#pragma unroll
    for (int mt = 0; mt < 4; mt++)
      af[mt] = *(const bf16x8*)(As[cur] + (wm + mt * 16 + fr) * 32 + koff);
#pragma unroll
    for (int nt = 0; nt < 4; nt++)
      bfr[nt] = *(const bf16x8*)(Bs[cur] + (wn + nt * 16 + fr) * 32 + koff);
#pragma unroll
    for (int mt = 0; mt < 4; mt++)
#pragma unroll
      for (int nt = 0; nt < 4; nt++)
        acc[mt][nt] = __builtin_amdgcn_mfma_f32_16x16x32_bf16(af[mt], bfr[nt], acc[mt][nt], 0, 0, 0);
    __syncthreads();   // drains prefetch (vmcnt) + frag reads (lgkm); flip
    cur ^= 1;
  }
  const int crow = (lane >> 4) * 4;
  float* pout = part + (size_t)r * 131072;
#pragma unroll
  for (int mt = 0; mt < 4; mt++)
#pragma unroll
    for (int nt = 0; nt < 4; nt++)
#pragma unroll
      for (int q = 0; q < 4; q++)
        pout[(wm + mt * 16 + crow + q) * 1024 + et * 128 + wn + nt * 16 + fr] = acc[mt][nt][q];
}

// ============ mid: mem_it = sum_r h2[it,b,r]*part[r,b,e]; prep next prev ========
__global__ __launch_bounds__(256) void mid_kernel(
    const float* __restrict__ part, const float* __restrict__ h2,
    const float* __restrict__ att, const float* __restrict__ x,
    float* __restrict__ mem, unsigned short* __restrict__ prev_bf, int it) {
  const int idx = blockIdx.x * 256 + threadIdx.x;   // 131072
  const int b = idx >> 10, e = idx & 1023;
  const float* h2row = h2 + (it * B_ + b) * R_;     // b uniform per block
  const float* pp = part + idx;
  float s = 0.f;
#pragma unroll 8
  for (int rr = 0; rr < 64; rr++) s += h2row[rr] * pp[(size_t)rr * 131072];
  mem[it * 131072 + idx] = s;
  if (it < 3) {
    const float* arow = att + ((it + 1) * B_ + b) * 4;
    float acc = arow[0] * x[b * IN_ + R_ + e];
    for (int k = 1; k <= it; k++) acc += arow[k] * mem[(k - 1) * 131072 + idx];
    acc += arow[it + 1] * s;
    prev_bf[idx] = f2bf(acc);
  }
}

// ============ fallback path (small ws): round-0 fp32-kb gemm ====================
__global__ __launch_bounds__(256) void prep_fp32_kernel(
    const float* __restrict__ x, const float* __restrict__ att,
    const float* __restrict__ mem, float* __restrict__ prev,
    float* __restrict__ newmem, int it) {
  const int idx = blockIdx.x * 256 + threadIdx.x;
  const int b = idx >> 10, e = idx & 1023;
  const float* arow = att + (it * B_ + b) * 4;
  float acc = arow[0] * x[b * IN_ + R_ + e];
  for (int k = 1; k <= it; k++)
    acc += arow[k] * mem[(k - 1) * (B_ * E_) + b * E_ + e];
  prev[idx] = acc;
  newmem[idx] = 0.f;
}

__global__ __launch_bounds__(256) void gemm_fp32_kernel(
    const float* __restrict__ prev, const float* __restrict__ h2,
    const float* __restrict__ kb, float* __restrict__ out) {
  __shared__ unsigned short As[128 * 40];
  __shared__ unsigned short Bs[128 * 40];
  __shared__ float h2s[128];
  const int tid = threadIdx.x;
  const int et = blockIdx.x;
  const int r = blockIdx.y;
  if (tid < 128) h2s[tid] = h2[tid * 64 + r];
  __syncthreads();
  const int row = tid >> 1;
  const int c0 = (tid & 1) * 16;
  const float hsc = h2s[row];
  const float* aptr = prev + row * 1024 + c0;
  const float* bptr = kb + (size_t)r * (1024u * 1024u) + (size_t)(et * 128 + row) * 1024 + c0;
  unsigned short* adst = As + row * 40 + c0;
  unsigned short* bdst = Bs + row * 40 + c0;
  const int wv = tid >> 6, lane = tid & 63;
  const int wm = (wv & 1) * 64, wn = (wv >> 1) * 64;
  const int fr = lane & 15, koff = (lane >> 4) * 8;
  f32x4 acc[4][4];
#pragma unroll
  for (int mt = 0; mt < 4; mt++)
#pragma unroll
    for (int nt = 0; nt < 4; nt++)
#pragma unroll
      for (int q = 0; q < 4; q++) acc[mt][nt][q] = 0.f;
  for (int kk = 0; kk < 32; kk++) {
    const float4 a0 = *(const float4*)(aptr + kk * 32);
    const float4 a1 = *(const float4*)(aptr + kk * 32 + 4);
    const float4 a2 = *(const float4*)(aptr + kk * 32 + 8);
    const float4 a3 = *(const float4*)(aptr + kk * 32 + 12);
    const float4 b0 = *(const float4*)(bptr + kk * 32);
    const float4 b1 = *(const float4*)(bptr + kk * 32 + 4);
    const float4 b2 = *(const float4*)(bptr + kk * 32 + 8);
    const float4 b3 = *(const float4*)(bptr + kk * 32 + 12);
    __syncthreads();
    uint4 u;
    u.x = pack2(a0.x * hsc, a0.y * hsc); u.y = pack2(a0.z * hsc, a0.w * hsc);
    u.z = pack2(a1.x * hsc, a1.y * hsc); u.w = pack2(a1.z * hsc, a1.w * hsc);
    *(uint4*)adst = u;
    u.x = pack2(a2.x * hsc, a2.y * hsc); u.y = pack2(a2.z * hsc, a2.w * hsc);
    u.z = pack2(a3.x * hsc, a3.y * hsc); u.w = pack2(a3.z * hsc, a3.w * hsc);
    *(uint4*)(adst + 8) = u;
    u.x = pack2(b0.x, b0.y); u.y = pack2(b0.z, b0.w);
    u.z = pack2(b1.x, b1.y); u.w = pack2(b1.z, b1.w);
    *(uint4*)bdst = u;
    u.x = pack2(b2.x, b2.y); u.y = pack2(b2.z, b2.w);
    u.z = pack2(b3.x, b3.y); u.w = pack2(b3.z, b3.w);
    *(uint4*)(bdst + 8) = u;
    __syncthreads();
    bf16x8 af[4], bfr[4];
#pragma unroll
    for (int mt = 0; mt < 4; mt++)
      af[mt] = *(const bf16x8*)(As + (wm + mt * 16 + fr) * 40 + koff);
#pragma unroll
    for (int nt = 0; nt < 4; nt++)
      bfr[nt] = *(const bf16x8*)(Bs + (wn + nt * 16 + fr) * 40 + koff);
#pragma unroll
    for (int mt = 0; mt < 4; mt++)
#pragma unroll
      for (int nt = 0; nt < 4; nt++)
        acc[mt][nt] = __builtin_amdgcn_mfma_f32_16x16x32_bf16(af[mt], bfr[nt], acc[mt][nt], 0, 0, 0);
  }
  const int crow = (lane >> 4) * 4;
  const int ccol = et * 128 + fr;
#pragma unroll
  for (int mt = 0; mt < 4; mt++)
#pragma unroll
    for (int nt = 0; nt < 4; nt++)
#pragma unroll
      for (int q = 0; q < 4; q++)
        atomicAdd(&out[(wm + mt * 16 + crow + q) * 1024 + ccol + wn + nt * 16], acc[mt][nt][q]);
}

// ============ score = sigmoid(-dot(mem4, tail)) =================================
__global__ __launch_bounds__(256) void score_kernel(
    const float* __restrict__ x, const float* __restrict__ mem4,
    float* __restrict__ out) {
  __shared__ float red[4];
  const int b = blockIdx.x, tid = threadIdx.x;
  float s = 0.f;
  for (int e = tid; e < E_; e += 256)
    s += mem4[b * E_ + e] * x[b * IN_ + R_ + E_ + e];
  s = wred_sum(s);
  if ((tid & 63) == 0) red[tid >> 6] = s;
  __syncthreads();
  if (tid == 0) {
    float t = red[0] + red[1] + red[2] + red[3];
    out[b] = 1.f / (1.f + expf(t));   // sigmoid(-t)
  }
}

extern "C" void kernel_launch(void* const* d_in, const int* in_sizes, int n_in,
                              void* d_out, int out_size, void* d_ws, size_t ws_size,
                              hipStream_t stream) {
  const float* x    = (const float*)d_in[0];
  const float* kb   = (const float*)d_in[1];
  const float* Wih0 = (const float*)d_in[2];
  const float* Whh0 = (const float*)d_in[3];
  const float* bih0 = (const float*)d_in[4];
  const float* bhh0 = (const float*)d_in[5];
  const float* Wih  = (const float*)d_in[6];
  const float* Whh  = (const float*)d_in[7];
  const float* bih  = (const float*)d_in[8];
  const float* bhh  = (const float*)d_in[9];

  float* ws    = (float*)d_ws;
  float* h2    = ws;                    // 32768
  float* att   = ws + 32768;            // 2048
  float* mem   = ws + 34816;            // 4*131072
  float* prevb = ws + 559104;           // 131072 (bf16 or fp32 prev)
  float* part  = ws + 690176;           // 64*131072 = 8388608
  float* kbbf  = ws + 9078784;          // 33554432 (64Mi bf16)
  const size_t need_big = (size_t)(9078784 + 33554432) * sizeof(float);  // ~170.5 MB
  const bool big = ws_size >= need_big;

  if (big) {
    // fused0: LSTM (128 blocks) + round-0 fp32-kb GEMM w/ kbbf production (512)
    fused0_kernel<<<640, 256, 0, stream>>>(x, kb, Wih0, Whh0, bih0, bhh0,
                                           Wih, Whh, bih, bhh,
                                           (unsigned short*)kbbf, part, h2, att);
    mid_kernel<<<512, 256, 0, stream>>>(part, h2, att, x, mem,
                                        (unsigned short*)prevb, 0);
    for (int i = 1; i < 4; i++) {
      gemm_bf_kernel<<<dim3(8, 64), 256, 0, stream>>>(
          (const unsigned short*)prevb, (const unsigned short*)kbbf, part);
      mid_kernel<<<512, 256, 0, stream>>>(part, h2, att, x, mem,
                                          (unsigned short*)prevb, i);
    }
  } else {
    // small-ws: LSTM via fused0's lstm branch only (grid=128 -> no gemm blocks);
    // gemm pointers unused by that branch, pass safe dummies inside ws.
    fused0_kernel<<<128, 256, 0, stream>>>(x, kb, Wih0, Whh0, bih0, bhh0,
                                           Wih, Whh, bih, bhh,
                                           (unsigned short*)prevb, mem, h2, att);
    for (int i = 0; i < 4; i++) {
      float* newmem = mem + i * (B_ * E_);
      prep_fp32_kernel<<<512, 256, 0, stream>>>(x, att, mem, prevb, newmem, i);
      gemm_fp32_kernel<<<dim3(8, 64), 256, 0, stream>>>(prevb, h2 + i * (B_ * R_), kb, newmem);
    }
  }
  score_kernel<<<128, 256, 0, stream>>>(x, mem + 3 * (B_ * E_), (float*)d_out);
}